// Round 8
// baseline (30.425 us; speedup 1.0000x reference)
//
#include <hip/hip_runtime.h>
#include <math.h>

// SPSA on f(x) = x0^2 + Q*x1^2, Q=8. Step is affine: x' = S(d,k) x,
//   S = I + [nw; nw*s] * [1, Q*s],  nw = -2*ak, s = d0*d1 in {-1,+1}.
//   ck cancels exactly. x_final = (prod_k S_k) x_init.
//
// Two-kernel split (R7: 29.9us). R8 change: seg_kernel loads int4 =
// 16 B/lane (the m13 6.29 TB/s shape) -> each lane carries TWO adjacent
// trajectories; VMEM inst count halves, per-wave in-flight doubles.
//  k1: (bs/128 x 32seg) grid, 64-thr blocks, UNCAPPED (512 VGPR budget),
//      32 unconditional dwordx4 loads/thread. ws <- 2x2 products.
//  k2: order-preserving LDS tree fold of 32 matrices/traj (verified R6/R7).

#define SEGLEN 32
#define NSEG   32
#define NTAB   (NSEG * SEGLEN)   // 1024; main path requires n <= NTAB
#define TPJ    8                 // trajectories per block in combine kernel

__global__ __launch_bounds__(64) void seg_kernel(
    const int*   __restrict__ bits,    // (n, bs, 2) ints of {0,1}
    const float* __restrict__ a_arr,
    float4*      __restrict__ ws,      // (NSEG, bs) segment matrices
    int n, int bs, int A)
{
    __shared__ float s_nw[SEGLEN];

    const int lane = threadIdx.x;
    const int b0   = blockIdx.x * 128 + lane * 2;   // two trajs per lane
    const int seg  = blockIdx.y;
    const int k0   = seg * SEGLEN;
    const int kmax = n - 1;

    // Unconditional 32 x dwordx4 burst; index clamped, padded steps nw=0.
    const int4* p4  = (const int4*)bits;            // element = 2 trajs @ step k
    const int   row = bs >> 1;                      // int4 elements per step
    const int   col = b0 >> 1;
    int4 v[SEGLEN];
    #pragma unroll
    for (int j = 0; j < SEGLEN; ++j) {
        int k = k0 + j;
        k = (k > kmax) ? kmax : k;
        v[j] = p4[(size_t)k * row + col];
    }

    // Coefficient table while loads are in flight:
    //   nw[k] = -2*a[k]/(k+2+A)^0.602 for k<n, else 0 (identity step).
    if (lane < SEGLEN) {
        const int k = k0 + lane;
        float nw = 0.0f;
        if (k < n) nw = -2.0f * a_arr[k] / powf((float)(k + 2 + A), 0.602f);
        s_nw[lane] = nw;
    }
    __syncthreads();

    // Two segment products (trajs b0, b0+1), row-major 2x2 each.
    float a00 = 1.f, a01 = 0.f, a10 = 0.f, a11 = 1.f;
    float b00 = 1.f, b01 = 0.f, b10 = 0.f, b11 = 1.f;

    #pragma unroll
    for (int j = 0; j < SEGLEN; ++j) {
        const float nw = s_nw[j];
        {   // traj A: bits v[j].x, v[j].y
            unsigned sb = ((unsigned)(v[j].x ^ v[j].y)) << 31;
            float qs  = __uint_as_float(0x41000000u ^ sb);      // +-8.0
            float nws = __uint_as_float(__float_as_uint(nw) ^ sb);
            float u0 = fmaf(qs, a10, a00);
            float u1 = fmaf(qs, a11, a01);
            a00 = fmaf(nw,  u0, a00);
            a01 = fmaf(nw,  u1, a01);
            a10 = fmaf(nws, u0, a10);
            a11 = fmaf(nws, u1, a11);
        }
        {   // traj B: bits v[j].z, v[j].w
            unsigned sb = ((unsigned)(v[j].z ^ v[j].w)) << 31;
            float qs  = __uint_as_float(0x41000000u ^ sb);
            float nws = __uint_as_float(__float_as_uint(nw) ^ sb);
            float u0 = fmaf(qs, b10, b00);
            float u1 = fmaf(qs, b11, b01);
            b00 = fmaf(nw,  u0, b00);
            b01 = fmaf(nw,  u1, b01);
            b10 = fmaf(nws, u0, b10);
            b11 = fmaf(nws, u1, b11);
        }
    }

    float4* wrow = ws + (size_t)seg * bs + b0;
    wrow[0] = make_float4(a00, a01, a10, a11);
    wrow[1] = make_float4(b00, b01, b10, b11);
}

__global__ __launch_bounds__(256) void combine_kernel(
    const float2* __restrict__ X0,
    const float4* __restrict__ ws,     // (NSEG, bs)
    float2*       __restrict__ out,
    int bs)
{
    __shared__ float4 s_m[NSEG][TPJ];

    const int tid  = threadIdx.x;
    const int traj = tid & (TPJ - 1);
    const int seg  = tid >> 3;           // 0..31
    int b          = blockIdx.x * TPJ + traj;
    const bool act = (b < bs);
    if (!act) b = bs - 1;

    // Swizzled column: avoids 8-way bank conflicts on the float4 rows.
    s_m[seg][(traj + seg) & (TPJ - 1)] = ws[(size_t)seg * bs + b];

    // Order-preserving in-place pairwise tree (verified R6/R7):
    //   level lvl (stride str): s_m[p] <- s_m[p+str] * s_m[p], p = 2*seg*str.
    #pragma unroll
    for (int lvl = 0; lvl < 5; ++lvl) {
        const int str = 1 << lvl;
        const int h   = NSEG >> (lvl + 1);
        __syncthreads();
        if (seg < h) {
            const int pos = (seg * 2) * str;
            float4 L = s_m[pos]      [(traj + pos)       & (TPJ - 1)];
            float4 R = s_m[pos + str][(traj + pos + str) & (TPJ - 1)];
            float4 P;
            P.x = fmaf(R.x, L.x, R.y * L.z);
            P.y = fmaf(R.x, L.y, R.y * L.w);
            P.z = fmaf(R.z, L.x, R.w * L.z);
            P.w = fmaf(R.z, L.y, R.w * L.w);
            s_m[pos][(traj + pos) & (TPJ - 1)] = P;
        }
    }

    if (seg == 0 && act) {
        float4 M = s_m[0][traj];
        float2 xin = X0[b];
        float v0 = xin.x * 20.0f - 10.0f;
        float v1 = xin.y * 20.0f - 10.0f;
        float r0 = fmaf(M.x, v0, M.y * v1);
        float r1 = fmaf(M.z, v0, M.w * v1);
        out[b] = make_float2(r0, r1);
    }
}

// Correctness fallback (odd shapes). Never hit in this bench (n=1000, bs=16384).
__global__ void spsa_fallback(
    const float2* __restrict__ X0, const int2* __restrict__ bits,
    const float* __restrict__ a_arr, float2* __restrict__ out,
    int n, int bs, int A)
{
    int b = blockIdx.x * 256 + threadIdx.x;
    if (b >= bs) return;
    float2 xin = X0[b];
    float x0 = xin.x * 20.0f - 10.0f;
    float x1 = xin.y * 20.0f - 10.0f;
    for (int k = 0; k < n; ++k) {
        float nw = -2.0f * a_arr[k] / powf((float)(k + 2 + A), 0.602f);
        int2 d = bits[(size_t)k * bs + b];
        unsigned sb = ((unsigned)(d.x ^ d.y)) << 31;
        float qs  = __uint_as_float(0x41000000u ^ sb);
        float nws = __uint_as_float(__float_as_uint(nw) ^ sb);
        float u = fmaf(qs, x1, x0);
        x0 = fmaf(nw,  u, x0);
        x1 = fmaf(nws, u, x1);
    }
    out[b] = make_float2(x0, x1);
}

extern "C" void kernel_launch(void* const* d_in, const int* in_sizes, int n_in,
                              void* d_out, int out_size, void* d_ws, size_t ws_size,
                              hipStream_t stream) {
    const float2* X0   = (const float2*)d_in[0];
    const float*  a    = (const float*) d_in[1];
    // d_in[2] = c (cancels exactly, unused)
    const int*    bits = (const int*)   d_in[3];
    float2*       out  = (float2*)d_out;

    const int bs = in_sizes[0] / 2;
    const int n  = in_sizes[1];
    const int A  = (int)floor(0.1 * (double)n);

    const size_t ws_need = (size_t)NSEG * bs * sizeof(float4);
    if (n <= NTAB && (bs % 128) == 0 && ws_size >= ws_need) {
        dim3 g1(bs / 128, NSEG);
        seg_kernel<<<g1, 64, 0, stream>>>(bits, a, (float4*)d_ws, n, bs, A);
        const int g2 = (bs + TPJ - 1) / TPJ;
        combine_kernel<<<g2, 256, 0, stream>>>(X0, (const float4*)d_ws, out, bs);
    } else {
        const int grid = (bs + 255) / 256;
        spsa_fallback<<<grid, 256, 0, stream>>>(X0, (const int2*)bits, a, out, n, bs, A);
    }
}

// Round 9
// 28.608 us; speedup vs baseline: 1.0635x; 1.0635x over previous
//
#include <hip/hip_runtime.h>
#include <math.h>

// SPSA on f(x) = x0^2 + Q*x1^2, Q=8. Step is affine: x' = S(d,k) x,
//   S = I + [nw; nw*s] * [1, Q*s],  nw = -2*ak, s = d0*d1 in {-1,+1}.
//   ck cancels exactly. x_final = (prod_k S_k) x_init.
//
// Two-kernel split (R7: 29.9us @ NSEG=32). R9: NSEG=16, seglen=64 ->
// ws traffic halves (8.4 MB total), combine halves, 64-deep int2 burst
// per thread (128 data VGPRs; 64-thr blocks UNCAPPED so no spill/serialize
// -- R2/R6 lesson). R8 showed int4 width is neutral: keep int2 contiguity.

#define SEGLEN 64
#define NSEG   16
#define NTAB   (NSEG * SEGLEN)   // 1024; main path requires n <= NTAB
#define TPJ    16                // trajectories per block in combine kernel

__global__ __launch_bounds__(64) void seg_kernel(
    const int2*  __restrict__ bits,    // (n, bs) int2 of {0,1} bits
    const float* __restrict__ a_arr,
    float4*      __restrict__ ws,      // (NSEG, bs) segment matrices
    int n, int bs, int A)
{
    __shared__ float s_nw[SEGLEN];

    const int lane = threadIdx.x;
    const int b    = blockIdx.x * 64 + lane;     // bs % 64 == 0 on main path
    const int seg  = blockIdx.y;
    const int k0   = seg * SEGLEN;
    const int kmax = n - 1;

    // Unconditional 64-load burst; index clamped, padded steps get nw=0.
    const int2* p = bits + b;
    int2 v[SEGLEN];
    #pragma unroll
    for (int j = 0; j < SEGLEN; ++j) {
        int k = k0 + j;
        k = (k > kmax) ? kmax : k;
        v[j] = p[(size_t)k * bs];
    }

    // Coefficient table while loads are in flight (one powf per lane):
    //   nw[k] = -2*a[k]/(k+2+A)^0.602 for k<n, else 0 (identity step).
    {
        const int k = k0 + lane;
        float nw = 0.0f;
        if (k < n) nw = -2.0f * a_arr[k] / powf((float)(k + 2 + A), 0.602f);
        s_nw[lane] = nw;
    }
    __syncthreads();

    // Segment product M = S_{k0+63} * ... * S_{k0}, row-major 2x2.
    float m00 = 1.f, m01 = 0.f, m10 = 0.f, m11 = 1.f;
    #pragma unroll
    for (int j = 0; j < SEGLEN; ++j) {
        const int2 d   = v[j];
        const float nw = s_nw[j];
        unsigned sb = ((unsigned)(d.x ^ d.y)) << 31;        // sign of s
        float qs  = __uint_as_float(0x41000000u ^ sb);      // +-8.0
        float nws = __uint_as_float(__float_as_uint(nw) ^ sb);
        float u0 = fmaf(qs, m10, m00);                      // [1,qs] . M
        float u1 = fmaf(qs, m11, m01);
        m00 = fmaf(nw,  u0, m00);
        m01 = fmaf(nw,  u1, m01);
        m10 = fmaf(nws, u0, m10);
        m11 = fmaf(nws, u1, m11);
    }

    ws[(size_t)seg * bs + b] = make_float4(m00, m01, m10, m11);
}

__global__ __launch_bounds__(256) void combine_kernel(
    const float2* __restrict__ X0,
    const float4* __restrict__ ws,     // (NSEG, bs)
    float2*       __restrict__ out,
    int bs)
{
    __shared__ float4 s_m[NSEG][TPJ];

    const int tid  = threadIdx.x;
    const int traj = tid & (TPJ - 1);
    const int seg  = tid >> 4;           // 0..15
    int b          = blockIdx.x * TPJ + traj;
    const bool act = (b < bs);
    if (!act) b = bs - 1;

    // Swizzled column: spreads tree-phase accesses across banks.
    s_m[seg][(traj + seg) & (TPJ - 1)] = ws[(size_t)seg * bs + b];

    // Order-preserving in-place pairwise tree (verified R6/R7/R8):
    //   level lvl (stride str): s_m[p] <- s_m[p+str] * s_m[p], p = 2*seg*str.
    #pragma unroll
    for (int lvl = 0; lvl < 4; ++lvl) {
        const int str = 1 << lvl;
        const int h   = NSEG >> (lvl + 1);
        __syncthreads();
        if (seg < h) {
            const int pos = (seg * 2) * str;
            float4 L = s_m[pos]      [(traj + pos)       & (TPJ - 1)];
            float4 R = s_m[pos + str][(traj + pos + str) & (TPJ - 1)];
            float4 P;
            P.x = fmaf(R.x, L.x, R.y * L.z);
            P.y = fmaf(R.x, L.y, R.y * L.w);
            P.z = fmaf(R.z, L.x, R.w * L.z);
            P.w = fmaf(R.z, L.y, R.w * L.w);
            s_m[pos][(traj + pos) & (TPJ - 1)] = P;
        }
    }

    if (seg == 0 && act) {
        float4 M = s_m[0][traj];
        float2 xin = X0[b];
        float v0 = xin.x * 20.0f - 10.0f;
        float v1 = xin.y * 20.0f - 10.0f;
        float r0 = fmaf(M.x, v0, M.y * v1);
        float r1 = fmaf(M.z, v0, M.w * v1);
        out[b] = make_float2(r0, r1);
    }
}

// Correctness fallback (odd shapes). Never hit in this bench (n=1000, bs=16384).
__global__ void spsa_fallback(
    const float2* __restrict__ X0, const int2* __restrict__ bits,
    const float* __restrict__ a_arr, float2* __restrict__ out,
    int n, int bs, int A)
{
    int b = blockIdx.x * 256 + threadIdx.x;
    if (b >= bs) return;
    float2 xin = X0[b];
    float x0 = xin.x * 20.0f - 10.0f;
    float x1 = xin.y * 20.0f - 10.0f;
    for (int k = 0; k < n; ++k) {
        float nw = -2.0f * a_arr[k] / powf((float)(k + 2 + A), 0.602f);
        int2 d = bits[(size_t)k * bs + b];
        unsigned sb = ((unsigned)(d.x ^ d.y)) << 31;
        float qs  = __uint_as_float(0x41000000u ^ sb);
        float nws = __uint_as_float(__float_as_uint(nw) ^ sb);
        float u = fmaf(qs, x1, x0);
        x0 = fmaf(nw,  u, x0);
        x1 = fmaf(nws, u, x1);
    }
    out[b] = make_float2(x0, x1);
}

extern "C" void kernel_launch(void* const* d_in, const int* in_sizes, int n_in,
                              void* d_out, int out_size, void* d_ws, size_t ws_size,
                              hipStream_t stream) {
    const float2* X0   = (const float2*)d_in[0];
    const float*  a    = (const float*) d_in[1];
    // d_in[2] = c (cancels exactly, unused)
    const int2*   bits = (const int2*)  d_in[3];
    float2*       out  = (float2*)d_out;

    const int bs = in_sizes[0] / 2;
    const int n  = in_sizes[1];
    const int A  = (int)floor(0.1 * (double)n);

    const size_t ws_need = (size_t)NSEG * bs * sizeof(float4);
    if (n <= NTAB && (bs % 64) == 0 && ws_size >= ws_need) {
        dim3 g1(bs / 64, NSEG);
        seg_kernel<<<g1, 64, 0, stream>>>(bits, a, (float4*)d_ws, n, bs, A);
        const int g2 = (bs + TPJ - 1) / TPJ;
        combine_kernel<<<g2, 256, 0, stream>>>(X0, (const float4*)d_ws, out, bs);
    } else {
        const int grid = (bs + 255) / 256;
        spsa_fallback<<<grid, 256, 0, stream>>>(X0, bits, a, out, n, bs, A);
    }
}

// Round 10
// 27.846 us; speedup vs baseline: 1.0926x; 1.0274x over previous
//
#include <hip/hip_runtime.h>
#include <math.h>

// SPSA on f(x) = x0^2 + Q*x1^2, Q=8. Step is affine: x' = S(d,k) x,
//   S = I + [nw; nw*s] * [1, Q*s],  nw = -2*ak, s = d0*d1 in {-1,+1}.
//   ck cancels exactly. x_final = (prod_k S_k) x_init.
//
// R10: FUSED single kernel. Block = 512 thr (8 waves) per 64 contiguous
// trajs; wave w computes segments 2w,2w+1 (two sequential 64-deep int2
// bursts, v[] reused); 16 matrices/traj in planar LDS (lane-stride 4B =
// 2-way bank alias, free per m136); order-preserving 4-level tree in-block;
// threads 0-63 apply M to x0 and store. Removes ws round-trip (8.4 MB),
// combine kernel, and launch gap vs R9 (28.6us).
// VGPR ~165 fits 512-thr block cap (256) with headroom (R6 trap: cap<need).

#define SEGLEN 64
#define NSEG   16
#define NTAB   (NSEG * SEGLEN)   // 1024; main path requires n <= NTAB
#define BLKT   512               // 8 waves

__global__ __launch_bounds__(BLKT) void spsa_fused(
    const float2* __restrict__ X0,
    const int2*   __restrict__ bits,   // (n, bs) int2 of {0,1} bits
    const float*  __restrict__ a_arr,
    float2*       __restrict__ out,
    int n, int bs, int A)
{
    __shared__ float s_nw[NTAB];
    __shared__ float s_m0[NSEG][64], s_m1[NSEG][64],
                     s_m2[NSEG][64], s_m3[NSEG][64];

    const int tid  = threadIdx.x;
    const int lane = tid & 63;
    const int wave = tid >> 6;            // 0..7
    const int b    = blockIdx.x * 64 + lane;   // bs % 64 == 0 on main path
    const int kmax = n - 1;

    const int segA = wave * 2;
    const int segB = wave * 2 + 1;
    const int kA   = segA * SEGLEN;
    const int kB   = segB * SEGLEN;
    const int2* p  = bits + b;

    // Burst A: 64 unconditional dwordx2 loads (index clamped; pads -> nw=0).
    int2 v[SEGLEN];
    #pragma unroll
    for (int j = 0; j < SEGLEN; ++j) {
        int k = kA + j;
        k = (k > kmax) ? kmax : k;
        v[j] = p[(size_t)k * bs];
    }

    // Coefficient table while burst A is in flight (2 entries/thread):
    //   nw[k] = -2*a[k]/(k+2+A)^0.602 for k<n, else 0 (identity step).
    #pragma unroll
    for (int t = 0; t < 2; ++t) {
        const int k = tid * 2 + t;
        float nw = 0.0f;
        if (k < n) nw = -2.0f * a_arr[k] / powf((float)(k + 2 + A), 0.602f);
        s_nw[k] = nw;
    }
    __syncthreads();                      // table ready (also drains burst A)

    auto stepm = [](int2 d, float nw, float& m00, float& m01,
                    float& m10, float& m11) {
        unsigned sb = ((unsigned)(d.x ^ d.y)) << 31;        // sign of s
        float qs  = __uint_as_float(0x41000000u ^ sb);      // +-8.0
        float nws = __uint_as_float(__float_as_uint(nw) ^ sb);
        float u0 = fmaf(qs, m10, m00);                      // [1,qs] . M
        float u1 = fmaf(qs, m11, m01);
        m00 = fmaf(nw,  u0, m00);
        m01 = fmaf(nw,  u1, m01);
        m10 = fmaf(nws, u0, m10);
        m11 = fmaf(nws, u1, m11);
    };

    // Segment 2w product (consumes v[j]; compiler may reload v[j] for
    // burst B right after its last use -- natural software pipeline).
    float a00 = 1.f, a01 = 0.f, a10 = 0.f, a11 = 1.f;
    #pragma unroll
    for (int j = 0; j < SEGLEN; ++j) stepm(v[j], s_nw[kA + j], a00, a01, a10, a11);

    // Burst B + segment 2w+1 product.
    #pragma unroll
    for (int j = 0; j < SEGLEN; ++j) {
        int k = kB + j;
        k = (k > kmax) ? kmax : k;
        v[j] = p[(size_t)k * bs];
    }
    float b00 = 1.f, b01 = 0.f, b10 = 0.f, b11 = 1.f;
    #pragma unroll
    for (int j = 0; j < SEGLEN; ++j) stepm(v[j], s_nw[kB + j], b00, b01, b10, b11);

    // Planar LDS stores (lane-stride 4 B -> conflict-free).
    s_m0[segA][lane] = a00; s_m1[segA][lane] = a01;
    s_m2[segA][lane] = a10; s_m3[segA][lane] = a11;
    s_m0[segB][lane] = b00; s_m1[segB][lane] = b01;
    s_m2[segB][lane] = b10; s_m3[segB][lane] = b11;

    // Order-preserving in-place pairwise tree over 16 segment matrices:
    //   level lvl (stride str): m[pos] <- m[pos+str] * m[pos], pos = 2*pair*str.
    const int pair = tid >> 6;            // == wave
    #pragma unroll
    for (int lvl = 0; lvl < 4; ++lvl) {
        const int str = 1 << lvl;
        const int h   = 8 >> lvl;         // pairs per traj at this level
        __syncthreads();
        if (pair < h) {
            const int pos = (pair * 2) * str;
            float L0 = s_m0[pos][lane],       L1 = s_m1[pos][lane];
            float L2 = s_m2[pos][lane],       L3 = s_m3[pos][lane];
            float R0 = s_m0[pos + str][lane], R1 = s_m1[pos + str][lane];
            float R2 = s_m2[pos + str][lane], R3 = s_m3[pos + str][lane];
            s_m0[pos][lane] = fmaf(R0, L0, R1 * L2);
            s_m1[pos][lane] = fmaf(R0, L1, R1 * L3);
            s_m2[pos][lane] = fmaf(R2, L0, R3 * L2);
            s_m3[pos][lane] = fmaf(R2, L1, R3 * L3);
        }
    }
    __syncthreads();

    if (tid < 64 && b < bs) {
        float M0 = s_m0[0][lane], M1 = s_m1[0][lane];
        float M2 = s_m2[0][lane], M3 = s_m3[0][lane];
        float2 xin = X0[b];
        float v0 = xin.x * 20.0f - 10.0f;
        float v1 = xin.y * 20.0f - 10.0f;
        float r0 = fmaf(M0, v0, M1 * v1);
        float r1 = fmaf(M2, v0, M3 * v1);
        out[b] = make_float2(r0, r1);
    }
}

// Correctness fallback (odd shapes). Never hit in this bench (n=1000, bs=16384).
__global__ void spsa_fallback(
    const float2* __restrict__ X0, const int2* __restrict__ bits,
    const float* __restrict__ a_arr, float2* __restrict__ out,
    int n, int bs, int A)
{
    int b = blockIdx.x * 256 + threadIdx.x;
    if (b >= bs) return;
    float2 xin = X0[b];
    float x0 = xin.x * 20.0f - 10.0f;
    float x1 = xin.y * 20.0f - 10.0f;
    for (int k = 0; k < n; ++k) {
        float nw = -2.0f * a_arr[k] / powf((float)(k + 2 + A), 0.602f);
        int2 d = bits[(size_t)k * bs + b];
        unsigned sb = ((unsigned)(d.x ^ d.y)) << 31;
        float qs  = __uint_as_float(0x41000000u ^ sb);
        float nws = __uint_as_float(__float_as_uint(nw) ^ sb);
        float u = fmaf(qs, x1, x0);
        x0 = fmaf(nw,  u, x0);
        x1 = fmaf(nws, u, x1);
    }
    out[b] = make_float2(x0, x1);
}

extern "C" void kernel_launch(void* const* d_in, const int* in_sizes, int n_in,
                              void* d_out, int out_size, void* d_ws, size_t ws_size,
                              hipStream_t stream) {
    const float2* X0   = (const float2*)d_in[0];
    const float*  a    = (const float*) d_in[1];
    // d_in[2] = c (cancels exactly, unused)
    const int2*   bits = (const int2*)  d_in[3];
    float2*       out  = (float2*)d_out;

    const int bs = in_sizes[0] / 2;
    const int n  = in_sizes[1];
    const int A  = (int)floor(0.1 * (double)n);

    if (n <= NTAB && (bs % 64) == 0) {
        spsa_fused<<<bs / 64, BLKT, 0, stream>>>(X0, bits, a, out, n, bs, A);
    } else {
        const int grid = (bs + 255) / 256;
        spsa_fallback<<<grid, 256, 0, stream>>>(X0, bits, a, out, n, bs, A);
    }
}

// Round 11
// 25.306 us; speedup vs baseline: 1.2023x; 1.1004x over previous
//
#include <hip/hip_runtime.h>
#include <math.h>

// SPSA on f(x) = x0^2 + Q*x1^2, Q=8. Step is affine: x' = S(d,k) x,
//   S = I + [nw; nw*s] * [1, Q*s],  nw = -2*ak, s = d0*d1 in {-1,+1}.
//   ck cancels exactly. x_final = (prod_k S_k) x_init.
//
// R11: fused kernel with R9-seg's streaming geometry. Block = 1024 thr
// (16 waves) per 64 contiguous trajs; wave w owns segment w (64 steps) as
// 4 x 16-deep burst/compute phases, single v[16] buffer (static indexing).
// 16 waves/CU (4/SIMD), ~8 KB outstanding/wave sustained -> ~5.6 TB/s
// pattern (R9-seg evidence). VGPR ~85 well under the 128 cap a 1024-thr
// block forces (R6 trap: 64-data-VGPR burst under cap 128 serialized).
// Tree combine + apply in-block as R10 (verified).

#define SEGLEN 64
#define NSEG   16
#define PH     4
#define PHL    16                 // loads per phase
#define NTAB   (NSEG * SEGLEN)    // 1024; main path requires n <= NTAB
#define BLKT   1024               // 16 waves

__global__ __launch_bounds__(BLKT) void spsa_fused(
    const float2* __restrict__ X0,
    const int2*   __restrict__ bits,   // (n, bs) int2 of {0,1} bits
    const float*  __restrict__ a_arr,
    float2*       __restrict__ out,
    int n, int bs, int A)
{
    __shared__ float s_nw[NTAB];
    __shared__ float s_m0[NSEG][64], s_m1[NSEG][64],
                     s_m2[NSEG][64], s_m3[NSEG][64];

    const int tid  = threadIdx.x;
    const int lane = tid & 63;
    const int wave = tid >> 6;            // 0..15 == segment id
    const int b    = blockIdx.x * 64 + lane;   // bs % 64 == 0 on main path
    const int kmax = n - 1;
    const int k0   = wave * SEGLEN;
    const int2* p  = bits + b;

    // Phase-0 burst first: 16 unconditional dwordx2 loads (clamped index;
    // padded steps get nw=0 -> identity).
    int2 v[PHL];
    #pragma unroll
    for (int j = 0; j < PHL; ++j) {
        int k = k0 + j;
        k = (k > kmax) ? kmax : k;
        v[j] = p[(size_t)k * bs];
    }

    // Coefficient table while phase-0 is in flight (1 entry/thread):
    //   nw[k] = -2*a[k]/(k+2+A)^0.602 for k<n, else 0 (identity step).
    {
        float nw = 0.0f;
        if (tid < n) nw = -2.0f * a_arr[tid] / powf((float)(tid + 2 + A), 0.602f);
        s_nw[tid] = nw;
    }
    __syncthreads();                      // table ready

    auto stepm = [](int2 d, float nw, float& m00, float& m01,
                    float& m10, float& m11) {
        unsigned sb = ((unsigned)(d.x ^ d.y)) << 31;        // sign of s
        float qs  = __uint_as_float(0x41000000u ^ sb);      // +-8.0
        float nws = __uint_as_float(__float_as_uint(nw) ^ sb);
        float u0 = fmaf(qs, m10, m00);                      // [1,qs] . M
        float u1 = fmaf(qs, m11, m01);
        m00 = fmaf(nw,  u0, m00);
        m01 = fmaf(nw,  u1, m01);
        m10 = fmaf(nws, u0, m10);
        m11 = fmaf(nws, u1, m11);
    };

    // Segment product M = S_{k0+63} * ... * S_{k0}, 4 pipelined phases.
    float m00 = 1.f, m01 = 0.f, m10 = 0.f, m11 = 1.f;
    #pragma unroll
    for (int ph = 0; ph < PH; ++ph) {
        #pragma unroll
        for (int j = 0; j < PHL; ++j) {
            stepm(v[j], s_nw[k0 + ph * PHL + j], m00, m01, m10, m11);
            if (ph + 1 < PH) {            // reload slot j for next phase
                int k = k0 + (ph + 1) * PHL + j;
                k = (k > kmax) ? kmax : k;
                v[j] = p[(size_t)k * bs];
            }
        }
    }

    // Planar LDS stores (lane-stride 4 B -> conflict-free).
    s_m0[wave][lane] = m00; s_m1[wave][lane] = m01;
    s_m2[wave][lane] = m10; s_m3[wave][lane] = m11;

    // Order-preserving in-place pairwise tree over 16 segment matrices:
    //   level lvl (stride str): m[pos] <- m[pos+str] * m[pos], pos = 2*pair*str.
    const int pair = wave;
    #pragma unroll
    for (int lvl = 0; lvl < 4; ++lvl) {
        const int str = 1 << lvl;
        const int h   = 8 >> lvl;         // pairs per traj at this level
        __syncthreads();
        if (pair < h) {
            const int pos = (pair * 2) * str;
            float L0 = s_m0[pos][lane],       L1 = s_m1[pos][lane];
            float L2 = s_m2[pos][lane],       L3 = s_m3[pos][lane];
            float R0 = s_m0[pos + str][lane], R1 = s_m1[pos + str][lane];
            float R2 = s_m2[pos + str][lane], R3 = s_m3[pos + str][lane];
            s_m0[pos][lane] = fmaf(R0, L0, R1 * L2);
            s_m1[pos][lane] = fmaf(R0, L1, R1 * L3);
            s_m2[pos][lane] = fmaf(R2, L0, R3 * L2);
            s_m3[pos][lane] = fmaf(R2, L1, R3 * L3);
        }
    }
    __syncthreads();

    if (tid < 64 && b < bs) {
        float M0 = s_m0[0][lane], M1 = s_m1[0][lane];
        float M2 = s_m2[0][lane], M3 = s_m3[0][lane];
        float2 xin = X0[b];
        float v0 = xin.x * 20.0f - 10.0f;
        float v1 = xin.y * 20.0f - 10.0f;
        float r0 = fmaf(M0, v0, M1 * v1);
        float r1 = fmaf(M2, v0, M3 * v1);
        out[b] = make_float2(r0, r1);
    }
}

// Correctness fallback (odd shapes). Never hit in this bench (n=1000, bs=16384).
__global__ void spsa_fallback(
    const float2* __restrict__ X0, const int2* __restrict__ bits,
    const float* __restrict__ a_arr, float2* __restrict__ out,
    int n, int bs, int A)
{
    int b = blockIdx.x * 256 + threadIdx.x;
    if (b >= bs) return;
    float2 xin = X0[b];
    float x0 = xin.x * 20.0f - 10.0f;
    float x1 = xin.y * 20.0f - 10.0f;
    for (int k = 0; k < n; ++k) {
        float nw = -2.0f * a_arr[k] / powf((float)(k + 2 + A), 0.602f);
        int2 d = bits[(size_t)k * bs + b];
        unsigned sb = ((unsigned)(d.x ^ d.y)) << 31;
        float qs  = __uint_as_float(0x41000000u ^ sb);
        float nws = __uint_as_float(__float_as_uint(nw) ^ sb);
        float u = fmaf(qs, x1, x0);
        x0 = fmaf(nw,  u, x0);
        x1 = fmaf(nws, u, x1);
    }
    out[b] = make_float2(x0, x1);
}

extern "C" void kernel_launch(void* const* d_in, const int* in_sizes, int n_in,
                              void* d_out, int out_size, void* d_ws, size_t ws_size,
                              hipStream_t stream) {
    const float2* X0   = (const float2*)d_in[0];
    const float*  a    = (const float*) d_in[1];
    // d_in[2] = c (cancels exactly, unused)
    const int2*   bits = (const int2*)  d_in[3];
    float2*       out  = (float2*)d_out;

    const int bs = in_sizes[0] / 2;
    const int n  = in_sizes[1];
    const int A  = (int)floor(0.1 * (double)n);

    if (n <= NTAB && (bs % 64) == 0) {
        spsa_fused<<<bs / 64, BLKT, 0, stream>>>(X0, bits, a, out, n, bs, A);
    } else {
        const int grid = (bs + 255) / 256;
        spsa_fallback<<<grid, 256, 0, stream>>>(X0, bits, a, out, n, bs, A);
    }
}

// Round 12
// 24.681 us; speedup vs baseline: 1.2327x; 1.0253x over previous
//
#include <hip/hip_runtime.h>
#include <math.h>

// SPSA on f(x) = x0^2 + Q*x1^2, Q=8. Step is affine: x' = S(d,k) x,
//   S = I + [nw; nw*s] * [1, Q*s],  nw = -2*ak, s = d0*d1 in {-1,+1}.
//   ck cancels exactly. x_final = (prod_k S_k) x_init.
//
// R12 = R11 (25.3us) + NON-TEMPORAL loads on the 131 MB read-once bits
// stream (nt flag -> no L1/L2 retention, removes eviction pressure; R5's
// full per-dispatch FETCH_SIZE showed L3 wasn't serving replays anyway).
// Bits loaded as one 64-bit scalar; sign = (lo^hi)<<31 in one xor.
// Structure: block = 1024 thr (16 waves) per 64 contiguous trajs; wave w
// owns segment w (64 steps) as 4 x 16-deep burst/compute phases (v[16],
// static indexing, ~32 data VGPRs -- R6 trap avoided). Planar-LDS
// order-preserving 4-level tree, apply + store by threads 0-63.

#define SEGLEN 64
#define NSEG   16
#define PH     4
#define PHL    16                 // loads per phase
#define NTAB   (NSEG * SEGLEN)    // 1024; main path requires n <= NTAB
#define BLKT   1024               // 16 waves

__global__ __launch_bounds__(BLKT) void spsa_fused(
    const float2* __restrict__ X0,
    const unsigned long long* __restrict__ bits,  // (n, bs) packed int2{0,1}
    const float*  __restrict__ a_arr,
    float2*       __restrict__ out,
    int n, int bs, int A)
{
    __shared__ float s_nw[NTAB];
    __shared__ float s_m0[NSEG][64], s_m1[NSEG][64],
                     s_m2[NSEG][64], s_m3[NSEG][64];

    const int tid  = threadIdx.x;
    const int lane = tid & 63;
    const int wave = tid >> 6;            // 0..15 == segment id
    const int b    = blockIdx.x * 64 + lane;   // bs % 64 == 0 on main path
    const int kmax = n - 1;
    const int k0   = wave * SEGLEN;
    const unsigned long long* p = bits + b;

    // Phase-0 burst first: 16 unconditional nt 8-byte loads (clamped index;
    // padded steps get nw=0 -> identity).
    unsigned long long v[PHL];
    #pragma unroll
    for (int j = 0; j < PHL; ++j) {
        int k = k0 + j;
        k = (k > kmax) ? kmax : k;
        v[j] = __builtin_nontemporal_load(p + (size_t)k * bs);
    }

    // Coefficient table while phase-0 is in flight (1 entry/thread):
    //   nw[k] = -2*a[k]/(k+2+A)^0.602 for k<n, else 0 (identity step).
    {
        float nw = 0.0f;
        if (tid < n) nw = -2.0f * a_arr[tid] / powf((float)(tid + 2 + A), 0.602f);
        s_nw[tid] = nw;
    }
    __syncthreads();                      // table ready

    auto stepm = [](unsigned long long d, float nw, float& m00, float& m01,
                    float& m10, float& m11) {
        unsigned sb = ((unsigned)d ^ (unsigned)(d >> 32)) << 31;  // sign of s
        float qs  = __uint_as_float(0x41000000u ^ sb);            // +-8.0
        float nws = __uint_as_float(__float_as_uint(nw) ^ sb);
        float u0 = fmaf(qs, m10, m00);                            // [1,qs] . M
        float u1 = fmaf(qs, m11, m01);
        m00 = fmaf(nw,  u0, m00);
        m01 = fmaf(nw,  u1, m01);
        m10 = fmaf(nws, u0, m10);
        m11 = fmaf(nws, u1, m11);
    };

    // Segment product M = S_{k0+63} * ... * S_{k0}, 4 pipelined phases.
    float m00 = 1.f, m01 = 0.f, m10 = 0.f, m11 = 1.f;
    #pragma unroll
    for (int ph = 0; ph < PH; ++ph) {
        #pragma unroll
        for (int j = 0; j < PHL; ++j) {
            stepm(v[j], s_nw[k0 + ph * PHL + j], m00, m01, m10, m11);
            if (ph + 1 < PH) {            // reload slot j for next phase
                int k = k0 + (ph + 1) * PHL + j;
                k = (k > kmax) ? kmax : k;
                v[j] = __builtin_nontemporal_load(p + (size_t)k * bs);
            }
        }
    }

    // Planar LDS stores (lane-stride 4 B -> conflict-free).
    s_m0[wave][lane] = m00; s_m1[wave][lane] = m01;
    s_m2[wave][lane] = m10; s_m3[wave][lane] = m11;

    // Order-preserving in-place pairwise tree over 16 segment matrices:
    //   level lvl (stride str): m[pos] <- m[pos+str] * m[pos], pos = 2*pair*str.
    const int pair = wave;
    #pragma unroll
    for (int lvl = 0; lvl < 4; ++lvl) {
        const int str = 1 << lvl;
        const int h   = 8 >> lvl;         // pairs per traj at this level
        __syncthreads();
        if (pair < h) {
            const int pos = (pair * 2) * str;
            float L0 = s_m0[pos][lane],       L1 = s_m1[pos][lane];
            float L2 = s_m2[pos][lane],       L3 = s_m3[pos][lane];
            float R0 = s_m0[pos + str][lane], R1 = s_m1[pos + str][lane];
            float R2 = s_m2[pos + str][lane], R3 = s_m3[pos + str][lane];
            s_m0[pos][lane] = fmaf(R0, L0, R1 * L2);
            s_m1[pos][lane] = fmaf(R0, L1, R1 * L3);
            s_m2[pos][lane] = fmaf(R2, L0, R3 * L2);
            s_m3[pos][lane] = fmaf(R2, L1, R3 * L3);
        }
    }
    __syncthreads();

    if (tid < 64 && b < bs) {
        float M0 = s_m0[0][lane], M1 = s_m1[0][lane];
        float M2 = s_m2[0][lane], M3 = s_m3[0][lane];
        float2 xin = X0[b];
        float v0 = xin.x * 20.0f - 10.0f;
        float v1 = xin.y * 20.0f - 10.0f;
        float r0 = fmaf(M0, v0, M1 * v1);
        float r1 = fmaf(M2, v0, M3 * v1);
        out[b] = make_float2(r0, r1);
    }
}

// Correctness fallback (odd shapes). Never hit in this bench (n=1000, bs=16384).
__global__ void spsa_fallback(
    const float2* __restrict__ X0, const int2* __restrict__ bits,
    const float* __restrict__ a_arr, float2* __restrict__ out,
    int n, int bs, int A)
{
    int b = blockIdx.x * 256 + threadIdx.x;
    if (b >= bs) return;
    float2 xin = X0[b];
    float x0 = xin.x * 20.0f - 10.0f;
    float x1 = xin.y * 20.0f - 10.0f;
    for (int k = 0; k < n; ++k) {
        float nw = -2.0f * a_arr[k] / powf((float)(k + 2 + A), 0.602f);
        int2 d = bits[(size_t)k * bs + b];
        unsigned sb = ((unsigned)(d.x ^ d.y)) << 31;
        float qs  = __uint_as_float(0x41000000u ^ sb);
        float nws = __uint_as_float(__float_as_uint(nw) ^ sb);
        float u = fmaf(qs, x1, x0);
        x0 = fmaf(nw,  u, x0);
        x1 = fmaf(nws, u, x1);
    }
    out[b] = make_float2(x0, x1);
}

extern "C" void kernel_launch(void* const* d_in, const int* in_sizes, int n_in,
                              void* d_out, int out_size, void* d_ws, size_t ws_size,
                              hipStream_t stream) {
    const float2* X0   = (const float2*)d_in[0];
    const float*  a    = (const float*) d_in[1];
    // d_in[2] = c (cancels exactly, unused)
    const int2*   bits = (const int2*)  d_in[3];
    float2*       out  = (float2*)d_out;

    const int bs = in_sizes[0] / 2;
    const int n  = in_sizes[1];
    const int A  = (int)floor(0.1 * (double)n);

    if (n <= NTAB && (bs % 64) == 0) {
        spsa_fused<<<bs / 64, BLKT, 0, stream>>>(
            X0, (const unsigned long long*)bits, a, out, n, bs, A);
    } else {
        const int grid = (bs + 255) / 256;
        spsa_fallback<<<grid, 256, 0, stream>>>(X0, bits, a, out, n, bs, A);
    }
}